// Round 6
// baseline (4879.885 us; speedup 1.0000x reference)
//
#include <hip/hip_runtime.h>

#define NN 100000
#define NE 600000
#define NP 100096   // 391*256, padded node count
#define NB 391
#define WSTR 2308   // w1bs per-ks stride: 64*36+4 (skewed banks)

typedef float v4    __attribute__((ext_vector_type(4)));
typedef float f32x4 __attribute__((ext_vector_type(4)));
typedef short s16x4 __attribute__((ext_vector_type(4)));
typedef short s16x8 __attribute__((ext_vector_type(8)));

__device__ __forceinline__ short f2bf(float f) {
    unsigned u = __float_as_uint(f);
    u = (u + 0x7fffu + ((u >> 16) & 1u)) >> 16;
    return (short)u;
}

// ---------------------------------------------------------------------------
// CSR construction: histogram -> scan -> fill
// ---------------------------------------------------------------------------
__global__ __launch_bounds__(256) void hist_kernel(const int* __restrict__ ei,
                                                   int* __restrict__ deg) {
    int e = blockIdx.x * 256 + threadIdx.x;
    if (e < NE) atomicAdd(&deg[ei[e]], 1);
}

__global__ __launch_bounds__(256) void scan1_kernel(const int* __restrict__ deg,
                                                    int* __restrict__ partial,
                                                    int* __restrict__ bsum) {
    __shared__ int tmp[256];
    int t = threadIdx.x;
    int i = blockIdx.x * 256 + t;
    int v = deg[i];
    tmp[t] = v;
    __syncthreads();
    for (int off = 1; off < 256; off <<= 1) {
        int add = (t >= off) ? tmp[t - off] : 0;
        __syncthreads();
        tmp[t] += add;
        __syncthreads();
    }
    partial[i] = tmp[t] - v;
    if (t == 255) bsum[blockIdx.x] = tmp[255];
}

__global__ __launch_bounds__(512) void scan2_kernel(const int* __restrict__ bsum,
                                                    int* __restrict__ boff) {
    __shared__ int tmp[512];
    int t = threadIdx.x;
    int v = (t < NB) ? bsum[t] : 0;
    tmp[t] = v;
    __syncthreads();
    for (int off = 1; off < 512; off <<= 1) {
        int add = (t >= off) ? tmp[t - off] : 0;
        __syncthreads();
        tmp[t] += add;
        __syncthreads();
    }
    boff[t] = tmp[t] - v;
}

__global__ __launch_bounds__(256) void scan3_kernel(const int* __restrict__ partial,
                                                    const int* __restrict__ boff,
                                                    int* __restrict__ base,
                                                    int* __restrict__ cursor) {
    int i = blockIdx.x * 256 + threadIdx.x;
    int b = partial[i] + boff[blockIdx.x];
    base[i] = b;
    cursor[i] = b;
}

__global__ __launch_bounds__(256) void fill_kernel(const int* __restrict__ ei,
                                                   int* __restrict__ cursor,
                                                   int* __restrict__ csr) {
    int e = blockIdx.x * 256 + threadIdx.x;
    if (e < NE) {
        int r = ei[e];
        int p = atomicAdd(&cursor[r], 1);
        csr[p] = e;
    }
}

// ---------------------------------------------------------------------------
// Degree counting sort: nodes grouped by degree so waves are balanced.
// Output value per node is independent of within-bin order -> deterministic.
// ---------------------------------------------------------------------------
__global__ __launch_bounds__(256) void dhist_kernel(const int* __restrict__ deg,
                                                    int* __restrict__ dhist) {
    int i = blockIdx.x * 256 + threadIdx.x;
    if (i < NN) atomicAdd(&dhist[min(deg[i], 63)], 1);
}

__global__ __launch_bounds__(64) void dscan_kernel(const int* __restrict__ dhist,
                                                   int* __restrict__ dcur) {
    __shared__ int tmp[64];
    int t = threadIdx.x;
    int v = dhist[t];
    tmp[t] = v;
    __syncthreads();
    for (int off = 1; off < 64; off <<= 1) {
        int add = (t >= off) ? tmp[t - off] : 0;
        __syncthreads();
        tmp[t] += add;
        __syncthreads();
    }
    dcur[t] = tmp[t] - v;
}

__global__ __launch_bounds__(256) void dscatter_kernel(const int* __restrict__ deg,
                                                       int* __restrict__ dcur,
                                                       int* __restrict__ node_order) {
    int i = blockIdx.x * 256 + threadIdx.x;
    if (i < NN) {
        int b = min(deg[i], 63);
        int p = atomicAdd(&dcur[b], 1);
        node_order[p] = i;
    }
}

// ---------------------------------------------------------------------------
// Weight prep: W2aT [256][160] bf16 with z-reorder [agg(128), x(2), u(2), 0*28]
//              W2bT [512][256] bf16   (both B^T layout: [N][K], K contiguous)
// ---------------------------------------------------------------------------
__global__ __launch_bounds__(256) void prep_kernel(const float* __restrict__ W2a,
                                                   const float* __restrict__ W2b,
                                                   short* __restrict__ W2aT,
                                                   short* __restrict__ W2bT) {
    int idx = blockIdx.x * 256 + threadIdx.x;
    if (idx < 256 * 160) {
        int n = idx / 160, k = idx - n * 160;
        float v = 0.f;
        if (k < 128)       v = W2a[(2 + k) * 256 + n];
        else if (k == 128) v = W2a[0 * 256 + n];
        else if (k == 129) v = W2a[1 * 256 + n];
        else if (k == 130) v = W2a[130 * 256 + n];
        else if (k == 131) v = W2a[131 * 256 + n];
        W2aT[idx] = f2bf(v);
    }
    if (idx < 512 * 256) {
        int n = idx >> 8, k = idx & 255;
        W2bT[idx] = f2bf(W2b[k * 512 + n]);
    }
}

// ---------------------------------------------------------------------------
// agg2: 4 threads per node (k-split of 128 output cols into 4x32), nodes in
// degree-sorted order, 4 edges per iteration with h-presum (hS = sum of 4
// relu'd h1 vectors, one FMA per weight element). One pass over edges.
// agg = (sum_e h1_e @ W1b)/d + b1b  for d>0, else 0.
// ---------------------------------------------------------------------------
__global__ __launch_bounds__(256, 4) void agg2_kernel(
    const float* __restrict__ x, const int* __restrict__ ei,
    const float* __restrict__ ea,
    const float* __restrict__ W1a, const float* __restrict__ b1a,
    const float* __restrict__ W1b, const float* __restrict__ b1b,
    const int* __restrict__ base, const int* __restrict__ deg,
    const int* __restrict__ csr, const int* __restrict__ node_order,
    float* __restrict__ agg)
{
    __shared__ float w1a[256];
    __shared__ float ba[64];
    __shared__ float bbs[128];
    __shared__ float w1bs[4 * WSTR];   // [ks][k*36 + c], skewed per ks
    const int tid = threadIdx.x;

    w1a[tid] = W1a[tid];
    if (tid < 64)  ba[tid] = b1a[tid];
    if (tid < 128) bbs[tid] = b1b[tid];
    for (int idx = tid; idx < 8192; idx += 256) {
        int k = idx >> 7, c = idx & 127;
        w1bs[(c >> 5) * WSTR + k * 36 + (c & 31)] = W1b[idx];
    }
    __syncthreads();

    const int g  = blockIdx.x * 256 + tid;
    const int ni = g >> 2, ks = g & 3;
    const bool act = ni < NN;
    const int n  = act ? node_order[ni] : 0;
    const int d  = act ? deg[n] : 0;
    const int b0 = act ? base[n] : 0;
    const float* wslice = &w1bs[ks * WSTR];

    float acc[32];
#pragma unroll
    for (int c = 0; c < 32; ++c) acc[c] = 0.f;

    for (int i = 0; i < d; i += 4) {
        int eA = csr[b0 + i];
        bool vB = (i + 1) < d, vC = (i + 2) < d, vD = (i + 3) < d;
        int eB = vB ? csr[b0 + i + 1] : eA;
        int eC = vC ? csr[b0 + i + 2] : eA;
        int eD = vD ? csr[b0 + i + 3] : eA;
        int cA = ei[NE + eA], cB = ei[NE + eB];
        int cC = ei[NE + eC], cD = ei[NE + eD];
        float a0 = x[2 * cA], a1 = x[2 * cA + 1], a2 = ea[2 * eA], a3 = ea[2 * eA + 1];
        float b0f = x[2 * cB], b1f = x[2 * cB + 1], b2f = ea[2 * eB], b3f = ea[2 * eB + 1];
        float c0 = x[2 * cC], c1 = x[2 * cC + 1], c2 = ea[2 * eC], c3 = ea[2 * eC + 1];
        float d0 = x[2 * cD], d1 = x[2 * cD + 1], d2 = ea[2 * eD], d3 = ea[2 * eD + 1];

#pragma unroll
        for (int kg = 0; kg < 16; ++kg) {
            v4 r0 = *(const v4*)&w1a[kg * 4];
            v4 r1 = *(const v4*)&w1a[64 + kg * 4];
            v4 r2 = *(const v4*)&w1a[128 + kg * 4];
            v4 r3 = *(const v4*)&w1a[192 + kg * 4];
            v4 bb4 = *(const v4*)&ba[kg * 4];
            v4 hS;
#pragma unroll
            for (int m = 0; m < 4; ++m) {
                float va = bb4[m] + a0 * r0[m] + a1 * r1[m] + a2 * r2[m] + a3 * r3[m];
                float vb = bb4[m] + b0f * r0[m] + b1f * r1[m] + b2f * r2[m] + b3f * r3[m];
                float vc = bb4[m] + c0 * r0[m] + c1 * r1[m] + c2 * r2[m] + c3 * r3[m];
                float vd = bb4[m] + d0 * r0[m] + d1 * r1[m] + d2 * r2[m] + d3 * r3[m];
                float s = fmaxf(va, 0.f);
                if (vB) s += fmaxf(vb, 0.f);
                if (vC) s += fmaxf(vc, 0.f);
                if (vD) s += fmaxf(vd, 0.f);
                hS[m] = s;
            }
#pragma unroll
            for (int m = 0; m < 4; ++m) {
                const float* wr = &wslice[(kg * 4 + m) * 36];
#pragma unroll
                for (int cg = 0; cg < 8; ++cg) {
                    v4 w = *(const v4*)&wr[cg * 4];
#pragma unroll
                    for (int q = 0; q < 4; ++q)
                        acc[cg * 4 + q] += hS[m] * w[q];
                }
            }
        }
    }

    if (act) {
        float inv = (d > 0) ? 1.0f / (float)d : 0.f;
#pragma unroll
        for (int cg = 0; cg < 8; ++cg) {
            v4 o;
#pragma unroll
            for (int q = 0; q < 4; ++q) {
                int c = cg * 4 + q;
                o[q] = (d > 0) ? (acc[c] * inv + bbs[ks * 32 + c]) : 0.f;
            }
            *(v4*)&agg[(size_t)n * 128 + ks * 32 + cg * 4] = o;
        }
    }
}

// ---------------------------------------------------------------------------
// Node MFMA kernel (unchanged from R3/R5): 64 nodes/block, 8 waves, bf16 MFMA.
// ---------------------------------------------------------------------------
__global__ __launch_bounds__(512, 2) void node_mfma_kernel(
    const float* __restrict__ x, const float* __restrict__ u,
    const int* __restrict__ batch,
    const float* __restrict__ agg,
    const short* __restrict__ W2aT, const short* __restrict__ W2bT,
    const float* __restrict__ b2a, const float* __restrict__ b2b,
    float* __restrict__ out)
{
    __shared__ short zb[64 * 192];
    __shared__ short tb[64 * 256];
    const int tid = threadIdx.x;
    const int node0 = blockIdx.x * 64;

#pragma unroll
    for (int it = 0; it < 4; ++it) {
        int idx = it * 512 + tid;
        int r = idx >> 5, c = idx & 31;
        int node = node0 + r;
        f32x4 v = {0.f, 0.f, 0.f, 0.f};
        if (node < NN) v = *(const f32x4*)&agg[(size_t)node * 128 + c * 4];
        s16x4 p;
        p[0] = f2bf(v[0]); p[1] = f2bf(v[1]); p[2] = f2bf(v[2]); p[3] = f2bf(v[3]);
        int ch = c >> 1;
        int sw = (ch & ~7) | ((ch ^ r) & 7);
        *(s16x4*)&zb[r * 192 + sw * 8 + (c & 1) * 4] = p;
    }
    if (tid < 64) {
        int r = tid, node = node0 + r;
        s16x8 p = {0, 0, 0, 0, 0, 0, 0, 0};
        if (node < NN) {
            p[0] = f2bf(x[node * 2]); p[1] = f2bf(x[node * 2 + 1]);
            int b = batch[node];
            p[2] = f2bf(u[b * 2]); p[3] = f2bf(u[b * 2 + 1]);
        }
        int sw = 16 | (r & 7);
        *(s16x8*)&zb[r * 192 + sw * 8] = p;
    } else if (tid < 256) {
        int t2 = tid - 64;
        int r = t2 & 63;
        int ch = 17 + (t2 >> 6);
        int sw = (ch & ~7) | ((ch ^ r) & 7);
        s16x8 zz = {0, 0, 0, 0, 0, 0, 0, 0};
        *(s16x8*)&zb[r * 192 + sw * 8] = zz;
    }
    __syncthreads();

    const int lane = tid & 63, wid = tid >> 6;
    const int l15 = lane & 15, lk = lane >> 4;
    const int nw = wid;

    f32x4 acc1[4][2];
#pragma unroll
    for (int mf = 0; mf < 4; ++mf)
#pragma unroll
        for (int nf = 0; nf < 2; ++nf)
            acc1[mf][nf] = (f32x4){0.f, 0.f, 0.f, 0.f};

#pragma unroll
    for (int ks = 0; ks < 5; ++ks) {
        s16x8 a[4], b[2];
        int cb = ks * 4 + lk;
#pragma unroll
        for (int mf = 0; mf < 4; ++mf) {
            int r = mf * 16 + l15;
            int sw = (cb & ~7) | ((cb ^ r) & 7);
            a[mf] = *(const s16x8*)&zb[r * 192 + sw * 8];
        }
#pragma unroll
        for (int nf = 0; nf < 2; ++nf) {
            int n = nw * 32 + nf * 16 + l15;
            b[nf] = *(const s16x8*)&W2aT[n * 160 + ks * 32 + lk * 8];
        }
#pragma unroll
        for (int mf = 0; mf < 4; ++mf)
#pragma unroll
            for (int nf = 0; nf < 2; ++nf)
                acc1[mf][nf] = __builtin_amdgcn_mfma_f32_16x16x32_bf16(
                    a[mf], b[nf], acc1[mf][nf], 0, 0, 0);
    }

#pragma unroll
    for (int nf = 0; nf < 2; ++nf) {
        int n = nw * 32 + nf * 16 + l15;
        float bias = b2a[n];
        int ch = n >> 3, off = n & 7;
#pragma unroll
        for (int mf = 0; mf < 4; ++mf) {
#pragma unroll
            for (int j = 0; j < 4; ++j) {
                int r = mf * 16 + lk * 4 + j;
                float vv = fmaxf(acc1[mf][nf][j] + bias, 0.f);
                int sw = (ch & ~7) | ((ch ^ r) & 7);
                tb[r * 256 + sw * 8 + off] = f2bf(vv);
            }
        }
    }
    __syncthreads();

    f32x4 acc2[4][4];
#pragma unroll
    for (int mf = 0; mf < 4; ++mf)
#pragma unroll
        for (int nf = 0; nf < 4; ++nf)
            acc2[mf][nf] = (f32x4){0.f, 0.f, 0.f, 0.f};

#pragma unroll
    for (int ks = 0; ks < 8; ++ks) {
        s16x8 a[4], b[4];
        int cb = ks * 4 + lk;
#pragma unroll
        for (int mf = 0; mf < 4; ++mf) {
            int r = mf * 16 + l15;
            int sw = (cb & ~7) | ((cb ^ r) & 7);
            a[mf] = *(const s16x8*)&tb[r * 256 + sw * 8];
        }
#pragma unroll
        for (int nf = 0; nf < 4; ++nf) {
            int n = nw * 64 + nf * 16 + l15;
            b[nf] = *(const s16x8*)&W2bT[n * 256 + ks * 32 + lk * 8];
        }
#pragma unroll
        for (int mf = 0; mf < 4; ++mf)
#pragma unroll
            for (int nf = 0; nf < 4; ++nf)
                acc2[mf][nf] = __builtin_amdgcn_mfma_f32_16x16x32_bf16(
                    a[mf], b[nf], acc2[mf][nf], 0, 0, 0);
    }

#pragma unroll
    for (int nf = 0; nf < 4; ++nf) {
        int n = nw * 64 + nf * 16 + l15;
        float bias = b2b[n];
#pragma unroll
        for (int mf = 0; mf < 4; ++mf) {
#pragma unroll
            for (int j = 0; j < 4; ++j) {
                int r = mf * 16 + lk * 4 + j;
                int node = node0 + r;
                if (node < NN)
                    out[(size_t)node * 512 + n] = acc2[mf][nf][j] + bias;
            }
        }
    }
}

extern "C" void kernel_launch(void* const* d_in, const int* in_sizes, int n_in,
                              void* d_out, int out_size, void* d_ws, size_t ws_size,
                              hipStream_t stream) {
    const float* x          = (const float*)d_in[0];
    const int*   edge_index = (const int*)d_in[1];
    const float* edge_attr  = (const float*)d_in[2];
    const float* u          = (const float*)d_in[3];
    const int*   batch      = (const int*)d_in[4];
    const float* W1a        = (const float*)d_in[5];
    const float* b1a        = (const float*)d_in[6];
    const float* W1b        = (const float*)d_in[7];
    const float* b1b        = (const float*)d_in[8];
    const float* W2a        = (const float*)d_in[9];
    const float* b2a        = (const float*)d_in[10];
    const float* W2b        = (const float*)d_in[11];
    const float* b2b        = (const float*)d_in[12];
    float* out = (float*)d_out;

    // workspace layout
    float* agg    = (float*)d_ws;                        // [NN,128] fp32
    short* W2aT   = (short*)(agg + (size_t)NN * 128);    // [256,160] bf16
    short* W2bT   = W2aT + 256 * 160;                    // [512,256] bf16
    int*   deg    = (int*)(W2bT + 512 * 256);            // [NP]
    int*   dhist  = deg + NP;                            // [64] (memset with deg)
    int*   partial= dhist + 64;                          // [NP]
    int*   bsum   = partial + NP;                        // [512]
    int*   boff   = bsum + 512;                          // [512]
    int*   base   = boff + 512;                          // [NP]
    int*   cursor = base + NP;                           // [NP]
    int*   csr    = cursor + NP;                         // [NE]
    int*   norder = csr + NE;                            // [NP]
    int*   dcur   = norder + NP;                         // [64]

    hipMemsetAsync(deg, 0, (NP + 64) * sizeof(int), stream);

    prep_kernel <<<512, 256, 0, stream>>>(W2a, W2b, W2aT, W2bT);
    hist_kernel <<<(NE + 255) / 256, 256, 0, stream>>>(edge_index, deg);
    scan1_kernel<<<NB, 256, 0, stream>>>(deg, partial, bsum);
    scan2_kernel<<<1, 512, 0, stream>>>(bsum, boff);
    scan3_kernel<<<NB, 256, 0, stream>>>(partial, boff, base, cursor);
    fill_kernel <<<(NE + 255) / 256, 256, 0, stream>>>(edge_index, cursor, csr);

    dhist_kernel   <<<NB, 256, 0, stream>>>(deg, dhist);
    dscan_kernel   <<<1, 64, 0, stream>>>(dhist, dcur);
    dscatter_kernel<<<NB, 256, 0, stream>>>(deg, dcur, norder);

    agg2_kernel<<<(NN * 4 + 255) / 256, 256, 0, stream>>>(
        x, edge_index, edge_attr, W1a, b1a, W1b, b1b, base, deg, csr, norder, agg);

    node_mfma_kernel<<<(NN + 63) / 64, 512, 0, stream>>>(
        x, u, batch, agg, W2aT, W2bT, b2a, b2b, out);
}

// Round 7
// 4605.122 us; speedup vs baseline: 1.0597x; 1.0597x over previous
//
#include <hip/hip_runtime.h>

#define NN 100000
#define NE 600000
#define NP 100096   // 391*256, padded node count
#define NB 391
#define WSTR 2308   // w1bs per-ks stride: 64*36+4 (skewed banks)

typedef float v4    __attribute__((ext_vector_type(4)));
typedef float f32x4 __attribute__((ext_vector_type(4)));
typedef short s16x4 __attribute__((ext_vector_type(4)));
typedef short s16x8 __attribute__((ext_vector_type(8)));

__device__ __forceinline__ short f2bf(float f) {
    unsigned u = __float_as_uint(f);
    u = (u + 0x7fffu + ((u >> 16) & 1u)) >> 16;
    return (short)u;
}

// ---------------------------------------------------------------------------
// CSR construction: histogram -> scan -> fill
// ---------------------------------------------------------------------------
__global__ __launch_bounds__(256) void hist_kernel(const int* __restrict__ ei,
                                                   int* __restrict__ deg) {
    int e = blockIdx.x * 256 + threadIdx.x;
    if (e < NE) atomicAdd(&deg[ei[e]], 1);
}

__global__ __launch_bounds__(256) void scan1_kernel(const int* __restrict__ deg,
                                                    int* __restrict__ partial,
                                                    int* __restrict__ bsum) {
    __shared__ int tmp[256];
    int t = threadIdx.x;
    int i = blockIdx.x * 256 + t;
    int v = deg[i];
    tmp[t] = v;
    __syncthreads();
    for (int off = 1; off < 256; off <<= 1) {
        int add = (t >= off) ? tmp[t - off] : 0;
        __syncthreads();
        tmp[t] += add;
        __syncthreads();
    }
    partial[i] = tmp[t] - v;
    if (t == 255) bsum[blockIdx.x] = tmp[255];
}

__global__ __launch_bounds__(512) void scan2_kernel(const int* __restrict__ bsum,
                                                    int* __restrict__ boff) {
    __shared__ int tmp[512];
    int t = threadIdx.x;
    int v = (t < NB) ? bsum[t] : 0;
    tmp[t] = v;
    __syncthreads();
    for (int off = 1; off < 512; off <<= 1) {
        int add = (t >= off) ? tmp[t - off] : 0;
        __syncthreads();
        tmp[t] += add;
        __syncthreads();
    }
    boff[t] = tmp[t] - v;
}

__global__ __launch_bounds__(256) void scan3_kernel(const int* __restrict__ partial,
                                                    const int* __restrict__ boff,
                                                    int* __restrict__ base,
                                                    int* __restrict__ cursor) {
    int i = blockIdx.x * 256 + threadIdx.x;
    int b = partial[i] + boff[blockIdx.x];
    base[i] = b;
    cursor[i] = b;
}

__global__ __launch_bounds__(256) void fill_kernel(const int* __restrict__ ei,
                                                   int* __restrict__ cursor,
                                                   int* __restrict__ csr) {
    int e = blockIdx.x * 256 + threadIdx.x;
    if (e < NE) {
        int r = ei[e];
        int p = atomicAdd(&cursor[r], 1);
        csr[p] = e;
    }
}

// ---------------------------------------------------------------------------
// Degree counting sort: nodes grouped by degree so waves are balanced.
// ---------------------------------------------------------------------------
__global__ __launch_bounds__(256) void dhist_kernel(const int* __restrict__ deg,
                                                    int* __restrict__ dhist) {
    int i = blockIdx.x * 256 + threadIdx.x;
    if (i < NN) atomicAdd(&dhist[min(deg[i], 63)], 1);
}

__global__ __launch_bounds__(64) void dscan_kernel(const int* __restrict__ dhist,
                                                   int* __restrict__ dcur) {
    __shared__ int tmp[64];
    int t = threadIdx.x;
    int v = dhist[t];
    tmp[t] = v;
    __syncthreads();
    for (int off = 1; off < 64; off <<= 1) {
        int add = (t >= off) ? tmp[t - off] : 0;
        __syncthreads();
        tmp[t] += add;
        __syncthreads();
    }
    dcur[t] = tmp[t] - v;
}

__global__ __launch_bounds__(256) void dscatter_kernel(const int* __restrict__ deg,
                                                       int* __restrict__ dcur,
                                                       int* __restrict__ node_order) {
    int i = blockIdx.x * 256 + threadIdx.x;
    if (i < NN) {
        int b = min(deg[i], 63);
        int p = atomicAdd(&dcur[b], 1);
        node_order[p] = i;
    }
}

// ---------------------------------------------------------------------------
// Weight prep: W2aT [256][160] bf16 with z-reorder [agg(128), x(2), u(2), 0*28]
//              W2bT [512][256] bf16   (both B^T layout: [N][K], K contiguous)
// ---------------------------------------------------------------------------
__global__ __launch_bounds__(256) void prep_kernel(const float* __restrict__ W2a,
                                                   const float* __restrict__ W2b,
                                                   short* __restrict__ W2aT,
                                                   short* __restrict__ W2bT) {
    int idx = blockIdx.x * 256 + threadIdx.x;
    if (idx < 256 * 160) {
        int n = idx / 160, k = idx - n * 160;
        float v = 0.f;
        if (k < 128)       v = W2a[(2 + k) * 256 + n];
        else if (k == 128) v = W2a[0 * 256 + n];
        else if (k == 129) v = W2a[1 * 256 + n];
        else if (k == 130) v = W2a[130 * 256 + n];
        else if (k == 131) v = W2a[131 * 256 + n];
        W2aT[idx] = f2bf(v);
    }
    if (idx < 512 * 256) {
        int n = idx >> 8, k = idx & 255;
        W2bT[idx] = f2bf(W2b[k * 512 + n]);
    }
}

// ---------------------------------------------------------------------------
// agg2: 4 threads per node (k-split of 128 output cols into 4x32), nodes in
// degree-sorted order, 4 edges per iteration with h-presum. One edge pass.
// __launch_bounds__(256,2): R6's (256,4) forced VGPR=64 -> acc[] spilled to
// scratch (10 GB/dispatch observed). Cap 256 VGPR, no spill.
// ---------------------------------------------------------------------------
__global__ __launch_bounds__(256, 2) void agg2_kernel(
    const float* __restrict__ x, const int* __restrict__ ei,
    const float* __restrict__ ea,
    const float* __restrict__ W1a, const float* __restrict__ b1a,
    const float* __restrict__ W1b, const float* __restrict__ b1b,
    const int* __restrict__ base, const int* __restrict__ deg,
    const int* __restrict__ csr, const int* __restrict__ node_order,
    float* __restrict__ agg)
{
    __shared__ float w1a[256];
    __shared__ float ba[64];
    __shared__ float bbs[128];
    __shared__ float w1bs[4 * WSTR];   // [ks][k*36 + c], skewed per ks
    const int tid = threadIdx.x;

    w1a[tid] = W1a[tid];
    if (tid < 64)  ba[tid] = b1a[tid];
    if (tid < 128) bbs[tid] = b1b[tid];
    for (int idx = tid; idx < 8192; idx += 256) {
        int k = idx >> 7, c = idx & 127;
        w1bs[(c >> 5) * WSTR + k * 36 + (c & 31)] = W1b[idx];
    }
    __syncthreads();

    const int g  = blockIdx.x * 256 + tid;
    const int ni = g >> 2, ks = g & 3;
    const bool act = ni < NN;
    const int n  = act ? node_order[ni] : 0;
    const int d  = act ? deg[n] : 0;
    const int b0 = act ? base[n] : 0;
    const float* wslice = &w1bs[ks * WSTR];

    float acc[32];
#pragma unroll
    for (int c = 0; c < 32; ++c) acc[c] = 0.f;

    for (int i = 0; i < d; i += 4) {
        int eA = csr[b0 + i];
        bool vB = (i + 1) < d, vC = (i + 2) < d, vD = (i + 3) < d;
        int eB = vB ? csr[b0 + i + 1] : eA;
        int eC = vC ? csr[b0 + i + 2] : eA;
        int eD = vD ? csr[b0 + i + 3] : eA;
        int cA = ei[NE + eA], cB = ei[NE + eB];
        int cC = ei[NE + eC], cD = ei[NE + eD];
        float a0 = x[2 * cA], a1 = x[2 * cA + 1], a2 = ea[2 * eA], a3 = ea[2 * eA + 1];
        float b0f = x[2 * cB], b1f = x[2 * cB + 1], b2f = ea[2 * eB], b3f = ea[2 * eB + 1];
        float c0 = x[2 * cC], c1 = x[2 * cC + 1], c2 = ea[2 * eC], c3 = ea[2 * eC + 1];
        float d0 = x[2 * cD], d1 = x[2 * cD + 1], d2 = ea[2 * eD], d3 = ea[2 * eD + 1];

#pragma unroll
        for (int kg = 0; kg < 16; ++kg) {
            v4 r0 = *(const v4*)&w1a[kg * 4];
            v4 r1 = *(const v4*)&w1a[64 + kg * 4];
            v4 r2 = *(const v4*)&w1a[128 + kg * 4];
            v4 r3 = *(const v4*)&w1a[192 + kg * 4];
            v4 bb4 = *(const v4*)&ba[kg * 4];
            v4 hS;
#pragma unroll
            for (int m = 0; m < 4; ++m) {
                float va = bb4[m] + a0 * r0[m] + a1 * r1[m] + a2 * r2[m] + a3 * r3[m];
                float vb = bb4[m] + b0f * r0[m] + b1f * r1[m] + b2f * r2[m] + b3f * r3[m];
                float vc = bb4[m] + c0 * r0[m] + c1 * r1[m] + c2 * r2[m] + c3 * r3[m];
                float vd = bb4[m] + d0 * r0[m] + d1 * r1[m] + d2 * r2[m] + d3 * r3[m];
                float s = fmaxf(va, 0.f);
                if (vB) s += fmaxf(vb, 0.f);
                if (vC) s += fmaxf(vc, 0.f);
                if (vD) s += fmaxf(vd, 0.f);
                hS[m] = s;
            }
#pragma unroll
            for (int m = 0; m < 4; ++m) {
                const float* wr = &wslice[(kg * 4 + m) * 36];
#pragma unroll
                for (int cg = 0; cg < 8; ++cg) {
                    v4 w = *(const v4*)&wr[cg * 4];
#pragma unroll
                    for (int q = 0; q < 4; ++q)
                        acc[cg * 4 + q] += hS[m] * w[q];
                }
            }
        }
    }

    if (act) {
        float inv = (d > 0) ? 1.0f / (float)d : 0.f;
#pragma unroll
        for (int cg = 0; cg < 8; ++cg) {
            v4 o;
#pragma unroll
            for (int q = 0; q < 4; ++q) {
                int c = cg * 4 + q;
                o[q] = (d > 0) ? (acc[c] * inv + bbs[ks * 32 + c]) : 0.f;
            }
            *(v4*)&agg[(size_t)n * 128 + ks * 32 + cg * 4] = o;
        }
    }
}

// ---------------------------------------------------------------------------
// Node MFMA kernel (unchanged): 64 nodes/block, 8 waves, bf16 MFMA.
// ---------------------------------------------------------------------------
__global__ __launch_bounds__(512, 2) void node_mfma_kernel(
    const float* __restrict__ x, const float* __restrict__ u,
    const int* __restrict__ batch,
    const float* __restrict__ agg,
    const short* __restrict__ W2aT, const short* __restrict__ W2bT,
    const float* __restrict__ b2a, const float* __restrict__ b2b,
    float* __restrict__ out)
{
    __shared__ short zb[64 * 192];
    __shared__ short tb[64 * 256];
    const int tid = threadIdx.x;
    const int node0 = blockIdx.x * 64;

#pragma unroll
    for (int it = 0; it < 4; ++it) {
        int idx = it * 512 + tid;
        int r = idx >> 5, c = idx & 31;
        int node = node0 + r;
        f32x4 v = {0.f, 0.f, 0.f, 0.f};
        if (node < NN) v = *(const f32x4*)&agg[(size_t)node * 128 + c * 4];
        s16x4 p;
        p[0] = f2bf(v[0]); p[1] = f2bf(v[1]); p[2] = f2bf(v[2]); p[3] = f2bf(v[3]);
        int ch = c >> 1;
        int sw = (ch & ~7) | ((ch ^ r) & 7);
        *(s16x4*)&zb[r * 192 + sw * 8 + (c & 1) * 4] = p;
    }
    if (tid < 64) {
        int r = tid, node = node0 + r;
        s16x8 p = {0, 0, 0, 0, 0, 0, 0, 0};
        if (node < NN) {
            p[0] = f2bf(x[node * 2]); p[1] = f2bf(x[node * 2 + 1]);
            int b = batch[node];
            p[2] = f2bf(u[b * 2]); p[3] = f2bf(u[b * 2 + 1]);
        }
        int sw = 16 | (r & 7);
        *(s16x8*)&zb[r * 192 + sw * 8] = p;
    } else if (tid < 256) {
        int t2 = tid - 64;
        int r = t2 & 63;
        int ch = 17 + (t2 >> 6);
        int sw = (ch & ~7) | ((ch ^ r) & 7);
        s16x8 zz = {0, 0, 0, 0, 0, 0, 0, 0};
        *(s16x8*)&zb[r * 192 + sw * 8] = zz;
    }
    __syncthreads();

    const int lane = tid & 63, wid = tid >> 6;
    const int l15 = lane & 15, lk = lane >> 4;
    const int nw = wid;

    f32x4 acc1[4][2];
#pragma unroll
    for (int mf = 0; mf < 4; ++mf)
#pragma unroll
        for (int nf = 0; nf < 2; ++nf)
            acc1[mf][nf] = (f32x4){0.f, 0.f, 0.f, 0.f};

#pragma unroll
    for (int ks = 0; ks < 5; ++ks) {
        s16x8 a[4], b[2];
        int cb = ks * 4 + lk;
#pragma unroll
        for (int mf = 0; mf < 4; ++mf) {
            int r = mf * 16 + l15;
            int sw = (cb & ~7) | ((cb ^ r) & 7);
            a[mf] = *(const s16x8*)&zb[r * 192 + sw * 8];
        }
#pragma unroll
        for (int nf = 0; nf < 2; ++nf) {
            int n = nw * 32 + nf * 16 + l15;
            b[nf] = *(const s16x8*)&W2aT[n * 160 + ks * 32 + lk * 8];
        }
#pragma unroll
        for (int mf = 0; mf < 4; ++mf)
#pragma unroll
            for (int nf = 0; nf < 2; ++nf)
                acc1[mf][nf] = __builtin_amdgcn_mfma_f32_16x16x32_bf16(
                    a[mf], b[nf], acc1[mf][nf], 0, 0, 0);
    }

#pragma unroll
    for (int nf = 0; nf < 2; ++nf) {
        int n = nw * 32 + nf * 16 + l15;
        float bias = b2a[n];
        int ch = n >> 3, off = n & 7;
#pragma unroll
        for (int mf = 0; mf < 4; ++mf) {
#pragma unroll
            for (int j = 0; j < 4; ++j) {
                int r = mf * 16 + lk * 4 + j;
                float vv = fmaxf(acc1[mf][nf][j] + bias, 0.f);
                int sw = (ch & ~7) | ((ch ^ r) & 7);
                tb[r * 256 + sw * 8 + off] = f2bf(vv);
            }
        }
    }
    __syncthreads();

    f32x4 acc2[4][4];
#pragma unroll
    for (int mf = 0; mf < 4; ++mf)
#pragma unroll
        for (int nf = 0; nf < 4; ++nf)
            acc2[mf][nf] = (f32x4){0.f, 0.f, 0.f, 0.f};

#pragma unroll
    for (int ks = 0; ks < 8; ++ks) {
        s16x8 a[4], b[4];
        int cb = ks * 4 + lk;
#pragma unroll
        for (int mf = 0; mf < 4; ++mf) {
            int r = mf * 16 + l15;
            int sw = (cb & ~7) | ((cb ^ r) & 7);
            a[mf] = *(const s16x8*)&tb[r * 256 + sw * 8];
        }
#pragma unroll
        for (int nf = 0; nf < 4; ++nf) {
            int n = nw * 64 + nf * 16 + l15;
            b[nf] = *(const s16x8*)&W2bT[n * 256 + ks * 32 + lk * 8];
        }
#pragma unroll
        for (int mf = 0; mf < 4; ++mf)
#pragma unroll
            for (int nf = 0; nf < 4; ++nf)
                acc2[mf][nf] = __builtin_amdgcn_mfma_f32_16x16x32_bf16(
                    a[mf], b[nf], acc2[mf][nf], 0, 0, 0);
    }

#pragma unroll
    for (int nf = 0; nf < 4; ++nf) {
        int n = nw * 64 + nf * 16 + l15;
        float bias = b2b[n];
#pragma unroll
        for (int mf = 0; mf < 4; ++mf) {
#pragma unroll
            for (int j = 0; j < 4; ++j) {
                int r = mf * 16 + lk * 4 + j;
                int node = node0 + r;
                if (node < NN)
                    out[(size_t)node * 512 + n] = acc2[mf][nf][j] + bias;
            }
        }
    }
}

extern "C" void kernel_launch(void* const* d_in, const int* in_sizes, int n_in,
                              void* d_out, int out_size, void* d_ws, size_t ws_size,
                              hipStream_t stream) {
    const float* x          = (const float*)d_in[0];
    const int*   edge_index = (const int*)d_in[1];
    const float* edge_attr  = (const float*)d_in[2];
    const float* u          = (const float*)d_in[3];
    const int*   batch      = (const int*)d_in[4];
    const float* W1a        = (const float*)d_in[5];
    const float* b1a        = (const float*)d_in[6];
    const float* W1b        = (const float*)d_in[7];
    const float* b1b        = (const float*)d_in[8];
    const float* W2a        = (const float*)d_in[9];
    const float* b2a        = (const float*)d_in[10];
    const float* W2b        = (const float*)d_in[11];
    const float* b2b        = (const float*)d_in[12];
    float* out = (float*)d_out;

    // workspace layout
    float* agg    = (float*)d_ws;                        // [NN,128] fp32
    short* W2aT   = (short*)(agg + (size_t)NN * 128);    // [256,160] bf16
    short* W2bT   = W2aT + 256 * 160;                    // [512,256] bf16
    int*   deg    = (int*)(W2bT + 512 * 256);            // [NP]
    int*   dhist  = deg + NP;                            // [64] (memset with deg)
    int*   partial= dhist + 64;                          // [NP]
    int*   bsum   = partial + NP;                        // [512]
    int*   boff   = bsum + 512;                          // [512]
    int*   base   = boff + 512;                          // [NP]
    int*   cursor = base + NP;                           // [NP]
    int*   csr    = cursor + NP;                         // [NE]
    int*   norder = csr + NE;                            // [NP]
    int*   dcur   = norder + NP;                         // [64]

    hipMemsetAsync(deg, 0, (NP + 64) * sizeof(int), stream);

    prep_kernel <<<512, 256, 0, stream>>>(W2a, W2b, W2aT, W2bT);
    hist_kernel <<<(NE + 255) / 256, 256, 0, stream>>>(edge_index, deg);
    scan1_kernel<<<NB, 256, 0, stream>>>(deg, partial, bsum);
    scan2_kernel<<<1, 512, 0, stream>>>(bsum, boff);
    scan3_kernel<<<NB, 256, 0, stream>>>(partial, boff, base, cursor);
    fill_kernel <<<(NE + 255) / 256, 256, 0, stream>>>(edge_index, cursor, csr);

    dhist_kernel   <<<NB, 256, 0, stream>>>(deg, dhist);
    dscan_kernel   <<<1, 64, 0, stream>>>(dhist, dcur);
    dscatter_kernel<<<NB, 256, 0, stream>>>(deg, dcur, norder);

    agg2_kernel<<<(NN * 4 + 255) / 256, 256, 0, stream>>>(
        x, edge_index, edge_attr, W1a, b1a, W1b, b1b, base, deg, csr, norder, agg);

    node_mfma_kernel<<<(NN + 63) / 64, 512, 0, stream>>>(
        x, u, batch, agg, W2aT, W2bT, b2a, b2b, out);
}